// Round 1
// baseline (242.772 us; speedup 1.0000x reference)
//
#include <hip/hip_runtime.h>

#define BB 64
#define NN 512
#define CC 2
#define EPSF 1e-8f
#define SPLITS 64
#define NSLOT 10
// ws slots per batch (doubles):
// 0 edge_sum, 1 sim_sum, 2 dot, 3 na2, 4 nt2, 5 ent_sum, 6 con_sum,
// 7 count, 8 coord_mse_sum, 9 coord_smooth_sum

__global__ void zero_ws_kernel(double* ws) {
    int i = threadIdx.x + blockIdx.x * blockDim.x;
    if (i < BB * NSLOT) ws[i] = 0.0;
}

__device__ inline float wave_reduce_f(float v) {
    #pragma unroll
    for (int off = 32; off >= 1; off >>= 1) v += __shfl_down(v, off, 64);
    return v;
}

__device__ inline double wave_reduce_d(double v) {
    #pragma unroll
    for (int off = 32; off >= 1; off >>= 1) v += __shfl_down(v, off, 64);
    return v;
}

__global__ __launch_bounds__(256) void main_kernel(
    const float* __restrict__ am,    // adjacency_matrix (B,N,N)
    const float* __restrict__ rs,    // raw_similarity   (B,N,N)
    const float* __restrict__ adj,   // adjacency        (B,N,N)
    const float* __restrict__ pred,  // predicted_coords (B,N,C)
    const float* __restrict__ pts,   // points           (B,N,C)
    const void* __restrict__ mask_raw,
    double* __restrict__ ws)
{
    __shared__ float smask[NN];
    const int b     = blockIdx.x / SPLITS;
    const int chunk = blockIdx.x % SPLITS;
    const int tid   = threadIdx.x;

    // node_masks dtype detection: bool bytes -> byte[1]==1 (counts>=6), int32 -> byte[1]==0
    const unsigned char* m8 = (const unsigned char*)mask_raw;
    const bool is_bool = (m8[1] != 0);
    if (is_bool) {
        const unsigned char* mb = m8 + (size_t)b * NN;
        smask[tid]       = mb[tid]       ? 1.0f : 0.0f;
        smask[tid + 256] = mb[tid + 256] ? 1.0f : 0.0f;
    } else {
        const int* mi = (const int*)mask_raw + (size_t)b * NN;
        smask[tid]       = mi[tid]       ? 1.0f : 0.0f;
        smask[tid + 256] = mi[tid + 256] ? 1.0f : 0.0f;
    }
    __syncthreads();

    const float4* am4 = (const float4*)(am  + (size_t)b * NN * NN);
    const float4* rs4 = (const float4*)(rs  + (size_t)b * NN * NN);
    const float4* ad4 = (const float4*)(adj + (size_t)b * NN * NN);

    float edge_s = 0.f, sim_s = 0.f, dot_s = 0.f, na2_s = 0.f,
          nt2_s = 0.f, ent_s = 0.f, con_s = 0.f;

    #pragma unroll
    for (int j = 0; j < 4; ++j) {
        const int vidx = chunk * 1024 + j * 256 + tid;  // float4 index in batch plane
        const int e    = vidx * 4;                      // element index
        const int row  = e >> 9;
        const int col  = e & 511;
        const float mr = smask[row];
        const float4 p = am4[vidx];
        const float4 s = rs4[vidx];
        const float4 a = ad4[vidx];

        const float mc[4] = {smask[col], smask[col + 1], smask[col + 2], smask[col + 3]};
        const float pv[4] = {p.x, p.y, p.z, p.w};
        const float sv[4] = {s.x, s.y, s.z, s.w};
        const float av[4] = {a.x, a.y, a.z, a.w};

        #pragma unroll
        for (int k = 0; k < 4; ++k) {
            const float msk = mr * mc[k];
            const float pp = pv[k], aa = av[k], ss = sv[k];
            const float ts = aa * 0.9f + 0.05f;
            const float lp = __logf(pp);
            const float lq = __logf(1.0f - pp);
            edge_s += msk * (ts * lp + (1.0f - ts) * lq);
            const float dsim = ss - aa;
            sim_s += msk * dsim * dsim;
            dot_s += msk * pp * aa;
            na2_s += msk * pp * pp;
            nt2_s += msk * aa * aa;
            const float lpe = __logf(pp + EPSF);
            const float lqe = __logf(1.0f - pp + EPSF);
            ent_s += msk * (pp * lpe + (1.0f - pp) * lqe);
            con_s += msk * fabsf(pp - 0.5f);
        }
    }

    // per-wave reduction + per-batch double atomics
    edge_s = wave_reduce_f(edge_s);
    sim_s  = wave_reduce_f(sim_s);
    dot_s  = wave_reduce_f(dot_s);
    na2_s  = wave_reduce_f(na2_s);
    nt2_s  = wave_reduce_f(nt2_s);
    ent_s  = wave_reduce_f(ent_s);
    con_s  = wave_reduce_f(con_s);
    if ((tid & 63) == 0) {
        double* wb = ws + (size_t)b * NSLOT;
        atomicAdd(&wb[0], (double)edge_s);
        atomicAdd(&wb[1], (double)sim_s);
        atomicAdd(&wb[2], (double)dot_s);
        atomicAdd(&wb[3], (double)na2_s);
        atomicAdd(&wb[4], (double)nt2_s);
        atomicAdd(&wb[5], (double)ent_s);
        atomicAdd(&wb[6], (double)con_s);
    }

    // chunk 0 blocks also handle count + coord loss for their batch
    if (chunk == 0) {
        float cs = smask[tid] + smask[tid + 256];

        const float4* pr4 = (const float4*)(pred + (size_t)b * NN * CC);
        const float4* pt4 = (const float4*)(pts  + (size_t)b * NN * CC);
        const float4 pv = pr4[tid];
        const float4 qv = pt4[tid];
        const int n0 = 2 * tid, n1 = 2 * tid + 1;
        const float mm[4] = {smask[n0], smask[n0], smask[n1], smask[n1]};
        const float dd[4] = {pv.x - qv.x, pv.y - qv.y, pv.z - qv.z, pv.w - qv.w};
        float cmse = 0.f, csm = 0.f;
        #pragma unroll
        for (int k = 0; k < 4; ++k) {
            const float d = dd[k];
            const float ad = fabsf(d);
            cmse += mm[k] * d * d;
            csm  += mm[k] * ((ad < 1.0f) ? 0.5f * d * d : ad - 0.5f);
        }
        cs   = wave_reduce_f(cs);
        cmse = wave_reduce_f(cmse);
        csm  = wave_reduce_f(csm);
        if ((tid & 63) == 0) {
            double* wb = ws + (size_t)b * NSLOT;
            atomicAdd(&wb[7], (double)cs);
            atomicAdd(&wb[8], (double)cmse);
            atomicAdd(&wb[9], (double)csm);
        }
    }
}

__global__ __launch_bounds__(64) void finalize_kernel(
    const double* __restrict__ ws,
    const float* __restrict__ node_counts,
    const float* __restrict__ temperature,
    const float* __restrict__ residual_weight,
    float* __restrict__ out)
{
    const int b = threadIdx.x;  // 64 lanes == 64 batches
    const double* wb = ws + (size_t)b * NSLOT;
    const double edge = wb[0], sim = wb[1], dot = wb[2], na2 = wb[3],
                 nt2 = wb[4], ents = wb[5], cons = wb[6];
    const float cnt = (float)wb[7];
    const float cmse = (float)wb[8], csm = (float)wb[9];

    // per-batch ARI pieces
    const float n2  = fmaxf(cnt * cnt, 1.0f);
    const float na  = sqrtf((float)na2);
    const float nt  = sqrtf((float)nt2);
    const float cosv = (float)dot / (fmaxf(na, EPSF) * fmaxf(nt, EPSF));
    const float ent  = -(float)ents / n2;
    const float con  = (float)cons / n2;
    const float cond = (cnt > 5.0f && cnt <= 50.0f) ? 1.0f : 0.0f;
    const float ari  = cond * (-cosv - 0.2f * con);
    const float conf = cond * ent;

    // per-batch count (huber) loss
    const float dc  = node_counts[b] - cnt;
    const float adc = fabsf(dc);
    const float closs = (adc <= 1.0f) ? 0.5f * dc * dc : adc - 0.5f;

    // wave-wide totals
    const double edge_t = wave_reduce_d(edge);
    const double sim_t  = wave_reduce_d(sim);
    const double cnt_t  = wave_reduce_d((double)cnt);
    const double cnt2_t = wave_reduce_d((double)cnt * (double)cnt);
    const double cmse_t = wave_reduce_d((double)cmse);
    const double csm_t  = wave_reduce_d((double)csm);
    const float  closs_t = wave_reduce_f(closs);
    const float  ari_t   = wave_reduce_f(ari);
    const float  conf_t  = wave_reduce_f(conf);

    if (b == 0) {
        const float cnt2      = fmaxf((float)cnt2_t, 1.0f);
        const float cnt_coord = fmaxf((float)cnt_t * (float)CC, 1.0f);
        const float edge_loss = -(float)edge_t / cnt2;
        const float sim_loss  = (float)sim_t / cnt2;
        const float coord_mse    = (float)cmse_t / cnt_coord;
        const float coord_smooth = (float)csm_t / cnt_coord;
        const float coord_loss = 0.7f * coord_mse + 0.3f * coord_smooth;
        const float count_loss = closs_t / (float)BB;
        const float treg = fabsf(temperature[0] - 1.0f);
        const float rreg = fabsf(residual_weight[0] - 0.5f);
        const float total = coord_loss + 2.0f * edge_loss + 0.1f * count_loss
                          + 0.3f * sim_loss + 0.01f * (treg + rreg)
                          + (ari_t + 0.1f * conf_t);
        out[0] = total;
    }
}

extern "C" void kernel_launch(void* const* d_in, const int* in_sizes, int n_in,
                              void* d_out, int out_size, void* d_ws, size_t ws_size,
                              hipStream_t stream) {
    const float* pred = (const float*)d_in[0];  // predicted_coords
    const float* am   = (const float*)d_in[1];  // adjacency_matrix
    const float* ncnt = (const float*)d_in[2];  // node_counts
    const float* rs   = (const float*)d_in[3];  // raw_similarity
    const float* temp = (const float*)d_in[4];  // temperature
    const float* resw = (const float*)d_in[5];  // residual_weight
    const float* pts  = (const float*)d_in[6];  // points
    const float* adj  = (const float*)d_in[7];  // adjacency
    const void*  msk  = d_in[8];                // node_masks (bool or int32)
    float* out = (float*)d_out;
    double* ws = (double*)d_ws;

    zero_ws_kernel<<<3, 256, 0, stream>>>(ws);
    main_kernel<<<BB * SPLITS, 256, 0, stream>>>(am, rs, adj, pred, pts, msk, ws);
    finalize_kernel<<<1, 64, 0, stream>>>(ws, ncnt, temp, resw, out);
}

// Round 2
// 184.714 us; speedup vs baseline: 1.3143x; 1.3143x over previous
//
#include <hip/hip_runtime.h>

#define BB 64
#define NN 512
#define NB 8          // atomic buckets per (batch, slot)
#define BSTRIDE 64    // doubles per batch in ws
#define EPSF 1e-8f
// ws layout per batch (doubles, stride BSTRIDE):
//   [slot s in 0..6][bucket k in 0..7] at s*8+k   (edge, sim, dot, na2, nt2, ent, con)
//   56 = cnt, 57 = coord_mse_sum, 58 = coord_smooth_sum

__global__ void zero_ws_kernel(double* ws) {
    // grid 16 x 256 = 4096 doubles = BB * BSTRIDE exactly
    ws[threadIdx.x + blockIdx.x * 256] = 0.0;
}

__device__ inline float wave_reduce_f(float v) {
    #pragma unroll
    for (int off = 32; off >= 1; off >>= 1) v += __shfl_down(v, off, 64);
    return v;
}
__device__ inline double wave_reduce_d(double v) {
    #pragma unroll
    for (int off = 32; off >= 1; off >>= 1) v += __shfl_down(v, off, 64);
    return v;
}

__global__ __launch_bounds__(256) void main_kernel(
    const float* __restrict__ am,    // adjacency_matrix (B,N,N)
    const float* __restrict__ rs,    // raw_similarity   (B,N,N)
    const float* __restrict__ adj,   // adjacency        (B,N,N)
    const float* __restrict__ pred,  // predicted_coords (B,N,C)
    const float* __restrict__ pts,   // points           (B,N,C)
    const void* __restrict__ mask_raw,
    double* __restrict__ ws)
{
    const int bx    = blockIdx.x;
    const int b     = bx >> 7;      // 128 row-groups of 4 rows per batch
    const int group = bx & 127;
    const int tid   = threadIdx.x;
    const int lane  = tid & 63;
    const int wid   = tid >> 6;

    // ---- cnt from prefix mask (each wave reads its batch's 512-entry row) ----
    // dtype detect: bool bytes -> byte[1]==1 (cnt>=6 guarantees mask[0][1]); int32 -> 0
    const unsigned char* m8g = (const unsigned char*)mask_raw;
    int c;
    if (m8g[1] != 0) {
        const unsigned long long* mrow =
            (const unsigned long long*)(m8g + ((size_t)b << 9));
        c = __popcll(mrow[lane]);           // bytes are 0/1 -> popcount = sum
    } else {
        const int4* mrow = (const int4*)((const int*)mask_raw + ((size_t)b << 9));
        const int4 a0 = mrow[lane * 2], a1 = mrow[lane * 2 + 1];
        c = a0.x + a0.y + a0.z + a0.w + a1.x + a1.y + a1.z + a1.w;
    }
    #pragma unroll
    for (int off = 32; off >= 1; off >>= 1) c += __shfl_down(c, off, 64);
    const int cnt = __shfl(c, 0, 64);

    if (group * 4 >= cnt && group != 0) return;   // block-uniform early exit

    // ---- per-row accumulation (wave wid handles row r) ----
    float edge_s = 0.f, sim_s = 0.f, dot_s = 0.f, na2_s = 0.f,
          nt2_s = 0.f, ent_s = 0.f, con_s = 0.f;
    const int r = group * 4 + wid;
    if (r < cnt) {
        const size_t base = ((size_t)b << 18) + ((size_t)r << 9);
        const float4* p4 = (const float4*)(am  + base);
        const float4* s4 = (const float4*)(rs  + base);
        const float4* a4 = (const float4*)(adj + base);
        const int nv4 = (cnt + 3) >> 2;
        for (int vi = lane; vi < nv4; vi += 64) {
            const float4 p = p4[vi];
            const float4 s = s4[vi];
            const float4 a = a4[vi];
            const int col = vi << 2;
            const float pv[4] = {p.x, p.y, p.z, p.w};
            const float sv[4] = {s.x, s.y, s.z, s.w};
            const float av[4] = {a.x, a.y, a.z, a.w};
            #pragma unroll
            for (int k = 0; k < 4; ++k) {
                const float msk = (col + k < cnt) ? 1.0f : 0.0f;
                const float pp = pv[k], aa = av[k], ss = sv[k];
                const float ts = fmaf(aa, 0.9f, 0.05f);
                const float lp = __logf(pp);
                const float lq = __logf(1.0f - pp);
                edge_s += msk * fmaf(ts, lp - lq, lq);   // ts*lp+(1-ts)*lq
                const float d = ss - aa;
                sim_s += msk * d * d;
                dot_s += msk * pp * aa;
                na2_s += msk * pp * pp;
                nt2_s += msk * aa * aa;
                const float lpe = __logf(pp + EPSF);
                const float lqe = __logf(1.0f - pp + EPSF);
                ent_s += msk * fmaf(pp, lpe - lqe, lqe);
                con_s += msk * fabsf(pp - 0.5f);
            }
        }
    }

    __shared__ float sred[4][8];
    edge_s = wave_reduce_f(edge_s);
    sim_s  = wave_reduce_f(sim_s);
    dot_s  = wave_reduce_f(dot_s);
    na2_s  = wave_reduce_f(na2_s);
    nt2_s  = wave_reduce_f(nt2_s);
    ent_s  = wave_reduce_f(ent_s);
    con_s  = wave_reduce_f(con_s);
    if (lane == 0) {
        sred[wid][0] = edge_s; sred[wid][1] = sim_s; sred[wid][2] = dot_s;
        sred[wid][3] = na2_s;  sred[wid][4] = nt2_s; sred[wid][5] = ent_s;
        sred[wid][6] = con_s;
    }
    __syncthreads();
    if (tid == 0) {
        float v[7];
        #pragma unroll
        for (int s = 0; s < 7; ++s)
            v[s] = sred[0][s] + sred[1][s] + sred[2][s] + sred[3][s];
        double* wb = ws + (size_t)b * BSTRIDE;
        const int bucket = group & (NB - 1);
        #pragma unroll
        for (int s = 0; s < 7; ++s)
            atomicAdd(&wb[s * NB + bucket], (double)v[s]);
    }

    // ---- group 0: coord loss + cnt for this batch ----
    if (group == 0) {
        const float4* pr4 = (const float4*)(pred + ((size_t)b << 10));
        const float4* pt4 = (const float4*)(pts  + ((size_t)b << 10));
        const float4 pv = pr4[tid];
        const float4 qv = pt4[tid];
        const int n0 = tid * 2, n1 = tid * 2 + 1;
        const float mm[4] = {(n0 < cnt) ? 1.f : 0.f, (n0 < cnt) ? 1.f : 0.f,
                             (n1 < cnt) ? 1.f : 0.f, (n1 < cnt) ? 1.f : 0.f};
        const float dd[4] = {pv.x - qv.x, pv.y - qv.y, pv.z - qv.z, pv.w - qv.w};
        float cmse = 0.f, csm = 0.f;
        #pragma unroll
        for (int k = 0; k < 4; ++k) {
            const float d = dd[k];
            const float ad = fabsf(d);
            cmse += mm[k] * d * d;
            csm  += mm[k] * ((ad < 1.0f) ? 0.5f * d * d : ad - 0.5f);
        }
        cmse = wave_reduce_f(cmse);
        csm  = wave_reduce_f(csm);
        __syncthreads();          // make sure tid0 is done reading sred above
        if (lane == 0) { sred[wid][0] = cmse; sred[wid][1] = csm; }
        __syncthreads();
        if (tid == 0) {
            double* wb = ws + (size_t)b * BSTRIDE;
            wb[56] = (double)cnt;
            wb[57] = (double)(sred[0][0] + sred[1][0] + sred[2][0] + sred[3][0]);
            wb[58] = (double)(sred[0][1] + sred[1][1] + sred[2][1] + sred[3][1]);
        }
    }
}

__global__ __launch_bounds__(64) void finalize_kernel(
    const double* __restrict__ ws,
    const float* __restrict__ node_counts,
    const float* __restrict__ temperature,
    const float* __restrict__ residual_weight,
    float* __restrict__ out)
{
    const int b = threadIdx.x;  // 64 lanes == 64 batches
    const double* wb = ws + (size_t)b * BSTRIDE;
    double edge = 0, sim = 0, dot = 0, na2 = 0, nt2 = 0, ents = 0, cons = 0;
    #pragma unroll
    for (int k = 0; k < NB; ++k) {
        edge += wb[0 * NB + k]; sim  += wb[1 * NB + k]; dot  += wb[2 * NB + k];
        na2  += wb[3 * NB + k]; nt2  += wb[4 * NB + k]; ents += wb[5 * NB + k];
        cons += wb[6 * NB + k];
    }
    const float cnt  = (float)wb[56];
    const float cmse = (float)wb[57];
    const float csm  = (float)wb[58];

    // per-batch ARI pieces
    const float n2   = fmaxf(cnt * cnt, 1.0f);
    const float na   = sqrtf((float)na2);
    const float nt   = sqrtf((float)nt2);
    const float cosv = (float)dot / (fmaxf(na, EPSF) * fmaxf(nt, EPSF));
    const float ent  = -(float)ents / n2;
    const float con  = (float)cons / n2;
    const float cond = (cnt > 5.0f && cnt <= 50.0f) ? 1.0f : 0.0f;
    const float ari  = cond * (-cosv - 0.2f * con);
    const float conf = cond * ent;

    // per-batch count (huber) loss
    const float dc   = node_counts[b] - cnt;
    const float adc  = fabsf(dc);
    const float closs = (adc <= 1.0f) ? 0.5f * dc * dc : adc - 0.5f;

    // wave-wide totals
    const double edge_t = wave_reduce_d(edge);
    const double sim_t  = wave_reduce_d(sim);
    const double cnt_t  = wave_reduce_d((double)cnt);
    const double cnt2_t = wave_reduce_d((double)cnt * (double)cnt);
    const double cmse_t = wave_reduce_d((double)cmse);
    const double csm_t  = wave_reduce_d((double)csm);
    const float  closs_t = wave_reduce_f(closs);
    const float  ari_t   = wave_reduce_f(ari);
    const float  conf_t  = wave_reduce_f(conf);

    if (b == 0) {
        const float cnt2      = fmaxf((float)cnt2_t, 1.0f);
        const float cnt_coord = fmaxf((float)cnt_t * 2.0f, 1.0f);
        const float edge_loss = -(float)edge_t / cnt2;
        const float sim_loss  = (float)sim_t / cnt2;
        const float coord_mse    = (float)cmse_t / cnt_coord;
        const float coord_smooth = (float)csm_t / cnt_coord;
        const float coord_loss = 0.7f * coord_mse + 0.3f * coord_smooth;
        const float count_loss = closs_t / (float)BB;
        const float treg = fabsf(temperature[0] - 1.0f);
        const float rreg = fabsf(residual_weight[0] - 0.5f);
        const float total = coord_loss + 2.0f * edge_loss + 0.1f * count_loss
                          + 0.3f * sim_loss + 0.01f * (treg + rreg)
                          + (ari_t + 0.1f * conf_t);
        out[0] = total;
    }
}

extern "C" void kernel_launch(void* const* d_in, const int* in_sizes, int n_in,
                              void* d_out, int out_size, void* d_ws, size_t ws_size,
                              hipStream_t stream) {
    const float* pred = (const float*)d_in[0];  // predicted_coords
    const float* am   = (const float*)d_in[1];  // adjacency_matrix
    const float* ncnt = (const float*)d_in[2];  // node_counts
    const float* rs   = (const float*)d_in[3];  // raw_similarity
    const float* temp = (const float*)d_in[4];  // temperature
    const float* resw = (const float*)d_in[5];  // residual_weight
    const float* pts  = (const float*)d_in[6];  // points
    const float* adj  = (const float*)d_in[7];  // adjacency
    const void*  msk  = d_in[8];                // node_masks (bool or int32)
    float* out = (float*)d_out;
    double* ws = (double*)d_ws;

    zero_ws_kernel<<<16, 256, 0, stream>>>(ws);
    main_kernel<<<BB * 128, 256, 0, stream>>>(am, rs, adj, pred, pts, msk, ws);
    finalize_kernel<<<1, 64, 0, stream>>>(ws, ncnt, temp, resw, out);
}